// Round 10
// baseline (333.887 us; speedup 1.0000x reference)
//
#include <hip/hip_runtime.h>

#define HID   64
#define ENC_T 20
#define DEC_T 30
#define ROWS  32   // batch rows per workgroup: two 16-row MFMA n-tiles per wave
#define HS    72   // sH row stride in f16 elems: 144B = 16B-aligned

typedef _Float16 f16;
typedef _Float16 f16x8 __attribute__((ext_vector_type(8)));
typedef _Float16 f16x4 __attribute__((ext_vector_type(4)));
typedef float  f32x4  __attribute__((ext_vector_type(4)));
typedef float  f32x2  __attribute__((ext_vector_type(2)));
typedef unsigned int   uint_t;

#if __has_builtin(__builtin_amdgcn_exp2f)
#define EXP2F(x) __builtin_amdgcn_exp2f(x)
#else
#define EXP2F(x) exp2f(x)
#endif
#if __has_builtin(__builtin_amdgcn_rcpf)
#define RCPF(x) __builtin_amdgcn_rcpf(x)
#else
#define RCPF(x) (1.0f / (x))
#endif

#define L2E 1.4426950408889634f

__device__ __forceinline__ f32x2 exp2_2(f32x2 x) {
    f32x2 r; r[0] = EXP2F(x[0]); r[1] = EXP2F(x[1]); return r;
}
// 8 packed-pair inverses with 2 rcp (v_pk_mul tree; rcp is scalar trans).
__device__ __forceinline__ void batch_inv4_pk(f32x2 D0, f32x2 D1, f32x2 D2, f32x2 D3,
                                              f32x2& i0, f32x2& i1, f32x2& i2, f32x2& i3) {
    f32x2 m01 = D0 * D1;
    f32x2 m23 = D2 * D3;
    f32x2 p   = m01 * m23;
    f32x2 r;
    r[0] = RCPF(p[0]);
    r[1] = RCPF(p[1]);
    f32x2 r01 = r * m23;
    f32x2 r23 = r * m01;
    i0 = r01 * D1;
    i1 = r01 * D0;
    i2 = r23 * D3;
    i3 = r23 * D2;
}
// One v_rcp for four scalar reciprocals (c-tanh denominators).
__device__ __forceinline__ f32x4 batch_inv4(float D0, float D1, float D2, float D3) {
    float m01 = D0 * D1;
    float m23 = D2 * D3;
    float r   = RCPF(m01 * m23);
    float r01 = r * m23;
    float r23 = r * m01;
    f32x4 o;
    o[0] = r01 * D1;
    o[1] = r01 * D0;
    o[2] = r23 * D3;
    o[3] = r23 * D2;
    return o;
}

// 8 consecutive fp32 (scaled) -> f16 frag
__device__ __forceinline__ f16x8 load8h(const float* __restrict__ p, float s) {
    f16x8 r;
    #pragma unroll
    for (int u = 0; u < 8; ++u) r[u] = (f16)(p[u] * s);
    return r;
}

// launch_bounds cap model (measured R2/R4/R6/R7): VGPR cap ~= 256/N.
// N=2 -> 128 cap; est. need ~80 -> margin. N=3 (84) / N=4 (64) spilled earlier bodies.
__global__ __launch_bounds__(256, 2)
void lstm_seq2seq(const float* __restrict__ traj,
                  const float* __restrict__ WihE, const float* __restrict__ WhhE,
                  const float* __restrict__ bihE, const float* __restrict__ bhhE,
                  const float* __restrict__ WihD, const float* __restrict__ WhhD,
                  const float* __restrict__ bihD, const float* __restrict__ bhhD,
                  const float* __restrict__ Wpos, const float* __restrict__ bpos,
                  float* __restrict__ out)
{
    __shared__ __align__(16) f16   sH[2][ROWS * HS];    // h (single f16), double-buffered
    __shared__ __align__(16) f16x4 sXh[ROWS * ENC_T + ENC_T]; // {xh0,xh1,xl0,xl1} + 20 zero slots

    const int tid  = threadIdx.x;
    const int w    = tid >> 6;      // wave -> unit tile (units 16w..16w+15)
    const int lane = tid & 63;
    const int col  = lane & 15;     // n-index: batch row (group 0) for this lane
    const int quad = lane >> 4;     // m-quad: C rows = units 16w + quad*4 + r
    const int wg   = blockIdx.x;

    const float gsc[4] = { L2E, L2E, 2.0f * L2E, L2E };  // i,f,g(tanh),o pre-scales

    // ---- stage trajectory as preconverted f16 hi/lo blocks (once) ----
    {
        const float* src = traj + (size_t)wg * (ROWS * ENC_T * 2);
        for (int p = tid; p < ROWS * ENC_T; p += 256) {
            f32x2 xp = *(const f32x2*)(src + 2 * p);
            f16 xh0 = (f16)xp[0], xh1 = (f16)xp[1];
            f16x4 v;
            v[0] = xh0; v[1] = xh1;
            v[2] = (f16)(xp[0] - (float)xh0);
            v[3] = (f16)(xp[1] - (float)xh1);
            sXh[p] = v;
        }
        if (tid < ENC_T) {              // zero slots: quad!=0 lanes read here
            f16x4 zz = {};
            sXh[ROWS * ENC_T + tid] = zz;
        }
    }
    // ---- zero h buffer 0 ----
    {
        uint_t* hz = (uint_t*)&sH[0][0];
        for (int j = tid; j < ROWS * HS / 2; j += 256) hz[j] = 0;
    }

    // ---- encoder A-fragments (f16). bw[j][0..1]: Whh k-blocks (A[m=col][k]).
    //      bw[j][2]: x+bias fold block: k-slots {W0hi,W1hi,W0lo,W1lo,b_hi,b_lo} ----
    f16x8 bw[4][3];
    #pragma unroll
    for (int j = 0; j < 4; ++j) {
        int g = 64 * j + 16 * w + col;
        #pragma unroll
        for (int kb = 0; kb < 2; ++kb)
            bw[j][kb] = load8h(WhhE + g * 64 + kb * 32 + quad * 8, gsc[j]);
        float w0 = WihE[g * 2 + 0] * gsc[j];
        float w1 = WihE[g * 2 + 1] * gsc[j];
        float bs = (bihE[g] + bhhE[g]) * gsc[j];
        f16 w0h = (f16)w0, w1h = (f16)w1, bh = (f16)bs;
        f16 w0l = (f16)(w0 - (float)w0h);
        f16 w1l = (f16)(w1 - (float)w1h);
        f16 bl  = (f16)(bs - (float)bh);
        f16x8 a2 = {};
        if (quad == 0) {
            a2[0] = w0h; a2[1] = w1h; a2[2] = w0l; a2[3] = w1l; a2[4] = bh; a2[5] = bl;
        }
        bw[j][2] = a2;
    }

    // hoisted per-lane constants for the encoder B2 block
    const uint_t onesd = (quad == 0) ? 0x3C003C00u : 0u;     // f16 {1,1} or {0,0}
    const int xbase0 = (quad == 0) ? (col      * ENC_T) : (ROWS * ENC_T);  // g=0
    const int xbase1 = (quad == 0) ? ((col+16) * ENC_T) : (ROWS * ENC_T);  // g=1
    const f32x4 z4 = { 0.f, 0.f, 0.f, 0.f };                 // shared zero C

    const f32x2 one2  = { 1.f, 1.f };
    const f32x2 two2  = { 2.f, 2.f };
    const f32x2 mone2 = { -1.f, -1.f };
    const f32x2 msc2  = { -2.f * L2E, -2.f * L2E };

    f32x2 c2[2][2] = {{{0.f,0.f},{0.f,0.f}},{{0.f,0.f},{0.f,0.f}}};
    int buf = 0;

    __syncthreads();

    // =========================== ENCODER ===========================
    for (int t = 0; t < ENC_T; ++t) {
        #pragma unroll
        for (int g = 0; g < 2; ++g) {
            const int colg = col + 16 * g;
            union { f16x4 v; uint_t d[2]; } xfu;
            xfu.v = sXh[(g ? xbase1 : xbase0) + t];
            union { f16x8 v; uint_t d[4]; } b2u;
            b2u.d[0] = xfu.d[0];
            b2u.d[1] = xfu.d[1];
            b2u.d[2] = onesd;
            b2u.d[3] = 0;
            f16x8 b0 = *(const f16x8*)&sH[buf][colg * HS +  0 + quad * 8];
            f16x8 b1 = *(const f16x8*)&sH[buf][colg * HS + 32 + quad * 8];
            f32x4 acc[4];
            #pragma unroll
            for (int j = 0; j < 4; ++j) {
                acc[j] = __builtin_amdgcn_mfma_f32_16x16x32_f16(bw[j][2], b2u.v, z4, 0, 0, 0);
                acc[j] = __builtin_amdgcn_mfma_f32_16x16x32_f16(bw[j][0], b0, acc[j], 0, 0, 0);
                acc[j] = __builtin_amdgcn_mfma_f32_16x16x32_f16(bw[j][1], b1, acc[j], 0, 0, 0);
            }
            // packed-f32 elementwise over r-pairs
            f32x2 so2[2], cn2[2];
            #pragma unroll
            for (int rp = 0; rp < 2; ++rp) {
                f32x2 a0 = { acc[0][2*rp], acc[0][2*rp+1] };
                f32x2 a1 = { acc[1][2*rp], acc[1][2*rp+1] };
                f32x2 a2v = { acc[2][2*rp], acc[2][2*rp+1] };
                f32x2 a3 = { acc[3][2*rp], acc[3][2*rp+1] };
                f32x2 i0, i1, i2, i3;
                batch_inv4_pk(exp2_2(-a0) + one2, exp2_2(-a1) + one2,
                              exp2_2(-a2v) + one2, exp2_2(-a3) + one2,
                              i0, i1, i2, i3);
                f32x2 tg = __builtin_elementwise_fma(two2, i2, mone2);
                f32x2 cn = __builtin_elementwise_fma(i1, c2[g][rp], i0 * tg);
                c2[g][rp] = cn;
                cn2[rp] = cn;
                so2[rp] = i3;
            }
            float Dc[4];
            #pragma unroll
            for (int rp = 0; rp < 2; ++rp) {
                f32x2 xs = cn2[rp] * msc2;
                Dc[2*rp+0] = 1.f + EXP2F(fminf(fmaxf(xs[0], -30.f), 30.f));
                Dc[2*rp+1] = 1.f + EXP2F(fminf(fmaxf(xs[1], -30.f), 30.f));
            }
            f32x4 invc = batch_inv4(Dc[0], Dc[1], Dc[2], Dc[3]);
            f16x4 hh;
            #pragma unroll
            for (int rp = 0; rp < 2; ++rp) {
                f32x2 ic = { invc[2*rp], invc[2*rp+1] };
                f32x2 th = __builtin_elementwise_fma(two2, ic, mone2);
                f32x2 hn = so2[rp] * th;
                hh[2*rp+0] = (f16)hn[0];
                hh[2*rp+1] = (f16)hn[1];
            }
            *(f16x4*)&sH[buf ^ 1][colg * HS + 16 * w + quad * 4] = hh;
        }
        __syncthreads();
        buf ^= 1;
    }

    // ---- decoder A-fragments: Wc = (W_ih_dec + W_hh_dec)*gsc, f16 single.
    //      Bias as MFMA C-input (quad-indexed rows). ----
    f32x4 bD4[4];
    #pragma unroll
    for (int j = 0; j < 4; ++j) {
        int g = 64 * j + 16 * w + col;
        #pragma unroll
        for (int kb = 0; kb < 2; ++kb) {
            int off = g * 64 + kb * 32 + quad * 8;
            float tmp[8];
            #pragma unroll
            for (int u = 0; u < 8; ++u) tmp[u] = WihD[off + u] + WhhD[off + u];
            bw[j][kb] = load8h(tmp, gsc[j]);
        }
        #pragma unroll
        for (int r = 0; r < 4; ++r) {
            int gr = 64 * j + 16 * w + quad * 4 + r;   // C-row indexing
            bD4[j][r] = (bihD[gr] + bhhD[gr]) * gsc[j];
        }
    }

    // ---- projection A-fragments (hi/lo exact): A[m=col][k]; rows 0,1 = comps.
    //      Wave 0 computes the FULL projection (B-frags span all 64 units). ----
    f16x8 wpH[2], wpL[2];
    #pragma unroll
    for (int kb = 0; kb < 2; ++kb) {
        f16x8 hv = {}, lv = {};
        if (col < 2) {
            #pragma unroll
            for (int u = 0; u < 8; ++u) {
                float v = Wpos[col * 64 + kb * 32 + quad * 8 + u];
                f16 vh = (f16)v;
                hv[u] = vh;
                lv[u] = (f16)(v - (float)vh);
            }
        }
        wpH[kb] = hv; wpL[kb] = lv;
    }
    f32x4 pinit = { 0.f, 0.f, 0.f, 0.f };   // bias as C-init: rows 0,1 = comps
    if (quad == 0) { pinit[0] = bpos[0]; pinit[1] = bpos[1]; }

    // =========================== DECODER ===========================
    // Wave 0 projects h_state (= h_new of step t-1) each step -> out[t-1];
    // final h projected after the loop.
    for (int t = 0; t < DEC_T; ++t) {
        #pragma unroll
        for (int g = 0; g < 2; ++g) {
            const int colg = col + 16 * g;
            f16x8 b0 = *(const f16x8*)&sH[buf][colg * HS +  0 + quad * 8];
            f16x8 b1 = *(const f16x8*)&sH[buf][colg * HS + 32 + quad * 8];
            if (w == 0 && t > 0) {
                f32x4 pc = pinit;
                pc = __builtin_amdgcn_mfma_f32_16x16x32_f16(wpH[0], b0, pc, 0, 0, 0);
                pc = __builtin_amdgcn_mfma_f32_16x16x32_f16(wpH[1], b1, pc, 0, 0, 0);
                pc = __builtin_amdgcn_mfma_f32_16x16x32_f16(wpL[0], b0, pc, 0, 0, 0);
                pc = __builtin_amdgcn_mfma_f32_16x16x32_f16(wpL[1], b1, pc, 0, 0, 0);
                if (lane < 16) {
                    f32x2 ov = { pc[0], pc[1] };   // regs 0,1 = comps 0,1 for rows n=col
                    *(f32x2*)&out[((size_t)(wg * ROWS + g * 16 + col)) * (DEC_T * 2) + (t - 1) * 2] = ov;
                }
            }
            f32x4 acc[4];
            #pragma unroll
            for (int j = 0; j < 4; ++j) {
                acc[j] = __builtin_amdgcn_mfma_f32_16x16x32_f16(bw[j][0], b0, bD4[j], 0, 0, 0);
                acc[j] = __builtin_amdgcn_mfma_f32_16x16x32_f16(bw[j][1], b1, acc[j], 0, 0, 0);
            }
            // packed-f32 elementwise over r-pairs
            f32x2 so2[2], cn2[2];
            #pragma unroll
            for (int rp = 0; rp < 2; ++rp) {
                f32x2 a0 = { acc[0][2*rp], acc[0][2*rp+1] };
                f32x2 a1 = { acc[1][2*rp], acc[1][2*rp+1] };
                f32x2 a2v = { acc[2][2*rp], acc[2][2*rp+1] };
                f32x2 a3 = { acc[3][2*rp], acc[3][2*rp+1] };
                f32x2 i0, i1, i2, i3;
                batch_inv4_pk(exp2_2(-a0) + one2, exp2_2(-a1) + one2,
                              exp2_2(-a2v) + one2, exp2_2(-a3) + one2,
                              i0, i1, i2, i3);
                f32x2 tg = __builtin_elementwise_fma(two2, i2, mone2);
                f32x2 cn = __builtin_elementwise_fma(i1, c2[g][rp], i0 * tg);
                c2[g][rp] = cn;
                cn2[rp] = cn;
                so2[rp] = i3;
            }
            float Dc[4];
            #pragma unroll
            for (int rp = 0; rp < 2; ++rp) {
                f32x2 xs = cn2[rp] * msc2;
                Dc[2*rp+0] = 1.f + EXP2F(fminf(fmaxf(xs[0], -30.f), 30.f));
                Dc[2*rp+1] = 1.f + EXP2F(fminf(fmaxf(xs[1], -30.f), 30.f));
            }
            f32x4 invc = batch_inv4(Dc[0], Dc[1], Dc[2], Dc[3]);
            f16x4 hh;
            #pragma unroll
            for (int rp = 0; rp < 2; ++rp) {
                f32x2 ic = { invc[2*rp], invc[2*rp+1] };
                f32x2 th = __builtin_elementwise_fma(two2, ic, mone2);
                f32x2 hn = so2[rp] * th;
                hh[2*rp+0] = (f16)hn[0];
                hh[2*rp+1] = (f16)hn[1];
            }
            *(f16x4*)&sH[buf ^ 1][colg * HS + 16 * w + quad * 4] = hh;
        }
        __syncthreads();
        buf ^= 1;
    }

    // final projection: h after last decoder step -> out[DEC_T-1]
    if (w == 0) {
        #pragma unroll
        for (int g = 0; g < 2; ++g) {
            const int colg = col + 16 * g;
            f16x8 b0 = *(const f16x8*)&sH[buf][colg * HS +  0 + quad * 8];
            f16x8 b1 = *(const f16x8*)&sH[buf][colg * HS + 32 + quad * 8];
            f32x4 pc = pinit;
            pc = __builtin_amdgcn_mfma_f32_16x16x32_f16(wpH[0], b0, pc, 0, 0, 0);
            pc = __builtin_amdgcn_mfma_f32_16x16x32_f16(wpH[1], b1, pc, 0, 0, 0);
            pc = __builtin_amdgcn_mfma_f32_16x16x32_f16(wpL[0], b0, pc, 0, 0, 0);
            pc = __builtin_amdgcn_mfma_f32_16x16x32_f16(wpL[1], b1, pc, 0, 0, 0);
            if (lane < 16) {
                f32x2 ov = { pc[0], pc[1] };
                *(f32x2*)&out[((size_t)(wg * ROWS + g * 16 + col)) * (DEC_T * 2) + (DEC_T - 1) * 2] = ov;
            }
        }
    }
}

extern "C" void kernel_launch(void* const* d_in, const int* in_sizes, int n_in,
                              void* d_out, int out_size, void* d_ws, size_t ws_size,
                              hipStream_t stream) {
    const float* traj = (const float*)d_in[0];
    const float* WihE = (const float*)d_in[1];
    const float* WhhE = (const float*)d_in[2];
    const float* bihE = (const float*)d_in[3];
    const float* bhhE = (const float*)d_in[4];
    const float* WihD = (const float*)d_in[5];
    const float* WhhD = (const float*)d_in[6];
    const float* bihD = (const float*)d_in[7];
    const float* bhhD = (const float*)d_in[8];
    const float* Wpos = (const float*)d_in[9];
    const float* bpos = (const float*)d_in[10];
    float* out = (float*)d_out;

    const int B = in_sizes[0] / (ENC_T * 2);   // 65536
    const int grid = B / ROWS;                 // 2048 workgroups, 32 rows each

    lstm_seq2seq<<<grid, 256, 0, stream>>>(traj, WihE, WhhE, bihE, bhhE,
                                           WihD, WhhD, bihD, bhhD, Wpos, bpos, out);
}

// Round 11
// 322.348 us; speedup vs baseline: 1.0358x; 1.0358x over previous
//
#include <hip/hip_runtime.h>

#define HID   64
#define ENC_T 20
#define DEC_T 30
#define ROWS  32   // batch rows per workgroup: two 16-row MFMA n-tiles per wave
#define HS    72   // sH row stride in f16 elems: 144B = 16B-aligned

typedef _Float16 f16;
typedef _Float16 f16x8 __attribute__((ext_vector_type(8)));
typedef _Float16 f16x4 __attribute__((ext_vector_type(4)));
typedef float  f32x4  __attribute__((ext_vector_type(4)));
typedef float  f32x2  __attribute__((ext_vector_type(2)));
typedef unsigned int   uint_t;

#if __has_builtin(__builtin_amdgcn_exp2f)
#define EXP2F(x) __builtin_amdgcn_exp2f(x)
#else
#define EXP2F(x) exp2f(x)
#endif
#if __has_builtin(__builtin_amdgcn_rcpf)
#define RCPF(x) __builtin_amdgcn_rcpf(x)
#else
#define RCPF(x) (1.0f / (x))
#endif

#define L2E 1.4426950408889634f

__device__ __forceinline__ f32x2 exp2_2(f32x2 x) {
    f32x2 r; r[0] = EXP2F(x[0]); r[1] = EXP2F(x[1]); return r;
}
// 8 packed-pair inverses with 2 rcp (v_pk_mul tree; rcp is scalar trans).
__device__ __forceinline__ void batch_inv4_pk(f32x2 D0, f32x2 D1, f32x2 D2, f32x2 D3,
                                              f32x2& i0, f32x2& i1, f32x2& i2, f32x2& i3) {
    f32x2 m01 = D0 * D1;
    f32x2 m23 = D2 * D3;
    f32x2 p   = m01 * m23;
    f32x2 r;
    r[0] = RCPF(p[0]);
    r[1] = RCPF(p[1]);
    f32x2 r01 = r * m23;
    f32x2 r23 = r * m01;
    i0 = r01 * D1;
    i1 = r01 * D0;
    i2 = r23 * D3;
    i3 = r23 * D2;
}
// One v_rcp for four scalar reciprocals (c-tanh denominators).
__device__ __forceinline__ f32x4 batch_inv4(float D0, float D1, float D2, float D3) {
    float m01 = D0 * D1;
    float m23 = D2 * D3;
    float r   = RCPF(m01 * m23);
    float r01 = r * m23;
    float r23 = r * m01;
    f32x4 o;
    o[0] = r01 * D1;
    o[1] = r01 * D0;
    o[2] = r23 * D3;
    o[3] = r23 * D2;
    return o;
}

// 8 consecutive fp32 (scaled) -> f16 frag
__device__ __forceinline__ f16x8 load8h(const float* __restrict__ p, float s) {
    f16x8 r;
    #pragma unroll
    for (int u = 0; u < 8; ++u) r[u] = (f16)(p[u] * s);
    return r;
}

// launch_bounds cap model (measured R2/R4/R6/R7): VGPR cap ~= 256/N.
// N=2 -> 128 cap. R10 lesson: register pressure is the second axis —
// VGPR 60->104 halved occupancy and erased a 12% instruction-diet win.
__global__ __launch_bounds__(256, 2)
void lstm_seq2seq(const float* __restrict__ traj,
                  const float* __restrict__ WihE, const float* __restrict__ WhhE,
                  const float* __restrict__ bihE, const float* __restrict__ bhhE,
                  const float* __restrict__ WihD, const float* __restrict__ WhhD,
                  const float* __restrict__ bihD, const float* __restrict__ bhhD,
                  const float* __restrict__ Wpos, const float* __restrict__ bpos,
                  float* __restrict__ out)
{
    __shared__ __align__(16) f16   sH[2][ROWS * HS];    // h (single f16), double-buffered
    __shared__ __align__(16) f16x4 sXh[ROWS * ENC_T + ENC_T]; // {xh0,xh1,xl0,xl1} + 20 zero slots
    __shared__ __align__(16) float sP[2][ROWS * 8];     // [row][comp*4 + wave] per-wave sums

    const int tid  = threadIdx.x;
    const int w    = tid >> 6;      // wave -> unit tile (units 16w..16w+15)
    const int lane = tid & 63;
    const int col  = lane & 15;     // n-index: batch row (group 0) for this lane
    const int quad = lane >> 4;     // m-quad: C rows = units 16w + quad*4 + r
    const int wg   = blockIdx.x;

    const float gsc[4] = { L2E, L2E, 2.0f * L2E, L2E };  // i,f,g(tanh),o pre-scales

    // ---- stage trajectory as preconverted f16 hi/lo blocks (once) ----
    {
        const float* src = traj + (size_t)wg * (ROWS * ENC_T * 2);
        for (int p = tid; p < ROWS * ENC_T; p += 256) {
            f32x2 xp = *(const f32x2*)(src + 2 * p);
            f16 xh0 = (f16)xp[0], xh1 = (f16)xp[1];
            f16x4 v;
            v[0] = xh0; v[1] = xh1;
            v[2] = (f16)(xp[0] - (float)xh0);
            v[3] = (f16)(xp[1] - (float)xh1);
            sXh[p] = v;
        }
        if (tid < ENC_T) {              // zero slots: quad!=0 lanes read here
            f16x4 zz = {};
            sXh[ROWS * ENC_T + tid] = zz;
        }
    }
    // ---- zero h buffer 0 ----
    {
        uint_t* hz = (uint_t*)&sH[0][0];
        for (int j = tid; j < ROWS * HS / 2; j += 256) hz[j] = 0;
    }

    // ---- encoder A-fragments (f16). bw[j][0..1]: Whh k-blocks (A[m=col][k]).
    //      bw[j][2]: x+bias fold block: k-slots {W0hi,W1hi,W0lo,W1lo,b_hi,b_lo} ----
    f16x8 bw[4][3];
    #pragma unroll
    for (int j = 0; j < 4; ++j) {
        int g = 64 * j + 16 * w + col;
        #pragma unroll
        for (int kb = 0; kb < 2; ++kb)
            bw[j][kb] = load8h(WhhE + g * 64 + kb * 32 + quad * 8, gsc[j]);
        float w0 = WihE[g * 2 + 0] * gsc[j];
        float w1 = WihE[g * 2 + 1] * gsc[j];
        float bs = (bihE[g] + bhhE[g]) * gsc[j];
        f16 w0h = (f16)w0, w1h = (f16)w1, bh = (f16)bs;
        f16 w0l = (f16)(w0 - (float)w0h);
        f16 w1l = (f16)(w1 - (float)w1h);
        f16 bl  = (f16)(bs - (float)bh);
        f16x8 a2 = {};
        if (quad == 0) {
            a2[0] = w0h; a2[1] = w1h; a2[2] = w0l; a2[3] = w1l; a2[4] = bh; a2[5] = bl;
        }
        bw[j][2] = a2;
    }

    // hoisted per-lane constants for the encoder B2 block
    const uint_t onesd = (quad == 0) ? 0x3C003C00u : 0u;     // f16 {1,1} or {0,0}
    const int xbase0 = (quad == 0) ? (col      * ENC_T) : (ROWS * ENC_T);  // g=0
    const int xbase1 = (quad == 0) ? ((col+16) * ENC_T) : (ROWS * ENC_T);  // g=1
    const f32x4 z4 = { 0.f, 0.f, 0.f, 0.f };                 // shared zero C

    const f32x2 one2  = { 1.f, 1.f };
    const f32x2 two2  = { 2.f, 2.f };
    const f32x2 mone2 = { -1.f, -1.f };
    const f32x2 msc2  = { -2.f * L2E, -2.f * L2E };

    f32x2 c2[2][2] = {{{0.f,0.f},{0.f,0.f}},{{0.f,0.f},{0.f,0.f}}};
    int buf = 0;

    __syncthreads();

    // =========================== ENCODER ===========================
    for (int t = 0; t < ENC_T; ++t) {
        #pragma unroll
        for (int g = 0; g < 2; ++g) {
            const int colg = col + 16 * g;
            union { f16x4 v; uint_t d[2]; } xfu;
            xfu.v = sXh[(g ? xbase1 : xbase0) + t];
            union { f16x8 v; uint_t d[4]; } b2u;
            b2u.d[0] = xfu.d[0];
            b2u.d[1] = xfu.d[1];
            b2u.d[2] = onesd;
            b2u.d[3] = 0;
            f16x8 b0 = *(const f16x8*)&sH[buf][colg * HS +  0 + quad * 8];
            f16x8 b1 = *(const f16x8*)&sH[buf][colg * HS + 32 + quad * 8];
            f32x4 acc[4];
            #pragma unroll
            for (int j = 0; j < 4; ++j) {
                acc[j] = __builtin_amdgcn_mfma_f32_16x16x32_f16(bw[j][2], b2u.v, z4, 0, 0, 0);
                acc[j] = __builtin_amdgcn_mfma_f32_16x16x32_f16(bw[j][0], b0, acc[j], 0, 0, 0);
                acc[j] = __builtin_amdgcn_mfma_f32_16x16x32_f16(bw[j][1], b1, acc[j], 0, 0, 0);
            }
            // packed-f32 elementwise over r-pairs
            f32x2 so2[2], cn2[2];
            #pragma unroll
            for (int rp = 0; rp < 2; ++rp) {
                f32x2 a0 = { acc[0][2*rp], acc[0][2*rp+1] };
                f32x2 a1 = { acc[1][2*rp], acc[1][2*rp+1] };
                f32x2 a2v = { acc[2][2*rp], acc[2][2*rp+1] };
                f32x2 a3 = { acc[3][2*rp], acc[3][2*rp+1] };
                f32x2 i0, i1, i2, i3;
                batch_inv4_pk(exp2_2(-a0) + one2, exp2_2(-a1) + one2,
                              exp2_2(-a2v) + one2, exp2_2(-a3) + one2,
                              i0, i1, i2, i3);
                f32x2 tg = __builtin_elementwise_fma(two2, i2, mone2);
                f32x2 cn = __builtin_elementwise_fma(i1, c2[g][rp], i0 * tg);
                c2[g][rp] = cn;
                cn2[rp] = cn;
                so2[rp] = i3;
            }
            float Dc[4];
            #pragma unroll
            for (int rp = 0; rp < 2; ++rp) {
                f32x2 xs = cn2[rp] * msc2;
                Dc[2*rp+0] = 1.f + EXP2F(fminf(fmaxf(xs[0], -30.f), 30.f));
                Dc[2*rp+1] = 1.f + EXP2F(fminf(fmaxf(xs[1], -30.f), 30.f));
            }
            f32x4 invc = batch_inv4(Dc[0], Dc[1], Dc[2], Dc[3]);
            f16x4 hh;
            #pragma unroll
            for (int rp = 0; rp < 2; ++rp) {
                f32x2 ic = { invc[2*rp], invc[2*rp+1] };
                f32x2 th = __builtin_elementwise_fma(two2, ic, mone2);
                f32x2 hn = so2[rp] * th;
                hh[2*rp+0] = (f16)hn[0];
                hh[2*rp+1] = (f16)hn[1];
            }
            *(f16x4*)&sH[buf ^ 1][colg * HS + 16 * w + quad * 4] = hh;
        }
        __syncthreads();
        buf ^= 1;
    }

    // ---- decoder A-fragments: Wc = (W_ih_dec + W_hh_dec)*gsc, f16 single.
    //      Bias as MFMA C-input (quad-indexed rows). ----
    f32x4 bD4[4];
    #pragma unroll
    for (int j = 0; j < 4; ++j) {
        int g = 64 * j + 16 * w + col;
        #pragma unroll
        for (int kb = 0; kb < 2; ++kb) {
            int off = g * 64 + kb * 32 + quad * 8;
            float tmp[8];
            #pragma unroll
            for (int u = 0; u < 8; ++u) tmp[u] = WihD[off + u] + WhhD[off + u];
            bw[j][kb] = load8h(tmp, gsc[j]);
        }
        #pragma unroll
        for (int r = 0; r < 4; ++r) {
            int gr = 64 * j + 16 * w + quad * 4 + r;   // C-row indexing
            bD4[j][r] = (bihD[gr] + bhhD[gr]) * gsc[j];
        }
    }

    // projection constants as packed pairs: this lane's 4 units
    f32x2 wpA2[2], wpB2[2];
    #pragma unroll
    for (int rp = 0; rp < 2; ++rp) {
        int u = 16 * w + quad * 4 + 2 * rp;
        wpA2[rp][0] = Wpos[u];       wpA2[rp][1] = Wpos[u + 1];        // comp 0
        wpB2[rp][0] = Wpos[64 + u];  wpB2[rp][1] = Wpos[64 + u + 1];   // comp 1
    }
    // distributed reducer constants: 64 tasks = 32 rows x 2 comps, lanes<16 of ALL 4 waves
    const int   rrow  = w * 8 + (lane >> 1);   // 0..31
    const int   rcomp = lane & 1;
    const float bp    = bpos[rcomp];

    // =========================== DECODER ===========================
    for (int t = 0; t < DEC_T; ++t) {
        #pragma unroll
        for (int g = 0; g < 2; ++g) {
            const int colg = col + 16 * g;
            f16x8 b0 = *(const f16x8*)&sH[buf][colg * HS +  0 + quad * 8];
            f16x8 b1 = *(const f16x8*)&sH[buf][colg * HS + 32 + quad * 8];
            f32x4 acc[4];
            #pragma unroll
            for (int j = 0; j < 4; ++j) {
                acc[j] = __builtin_amdgcn_mfma_f32_16x16x32_f16(bw[j][0], b0, bD4[j], 0, 0, 0);
                acc[j] = __builtin_amdgcn_mfma_f32_16x16x32_f16(bw[j][1], b1, acc[j], 0, 0, 0);
            }
            // packed-f32 elementwise over r-pairs
            f32x2 so2[2], cn2[2];
            #pragma unroll
            for (int rp = 0; rp < 2; ++rp) {
                f32x2 a0 = { acc[0][2*rp], acc[0][2*rp+1] };
                f32x2 a1 = { acc[1][2*rp], acc[1][2*rp+1] };
                f32x2 a2v = { acc[2][2*rp], acc[2][2*rp+1] };
                f32x2 a3 = { acc[3][2*rp], acc[3][2*rp+1] };
                f32x2 i0, i1, i2, i3;
                batch_inv4_pk(exp2_2(-a0) + one2, exp2_2(-a1) + one2,
                              exp2_2(-a2v) + one2, exp2_2(-a3) + one2,
                              i0, i1, i2, i3);
                f32x2 tg = __builtin_elementwise_fma(two2, i2, mone2);
                f32x2 cn = __builtin_elementwise_fma(i1, c2[g][rp], i0 * tg);
                c2[g][rp] = cn;
                cn2[rp] = cn;
                so2[rp] = i3;
            }
            float Dc[4];
            #pragma unroll
            for (int rp = 0; rp < 2; ++rp) {
                f32x2 xs = cn2[rp] * msc2;
                Dc[2*rp+0] = 1.f + EXP2F(fminf(fmaxf(xs[0], -30.f), 30.f));
                Dc[2*rp+1] = 1.f + EXP2F(fminf(fmaxf(xs[1], -30.f), 30.f));
            }
            f32x4 invc = batch_inv4(Dc[0], Dc[1], Dc[2], Dc[3]);
            f16x4 hh;
            f32x2 pA = { 0.f, 0.f }, pB = { 0.f, 0.f };
            #pragma unroll
            for (int rp = 0; rp < 2; ++rp) {
                f32x2 ic = { invc[2*rp], invc[2*rp+1] };
                f32x2 th = __builtin_elementwise_fma(two2, ic, mone2);
                f32x2 hn = so2[rp] * th;
                pA = __builtin_elementwise_fma(hn, wpA2[rp], pA);
                pB = __builtin_elementwise_fma(hn, wpB2[rp], pB);
                hh[2*rp+0] = (f16)hn[0];
                hh[2*rp+1] = (f16)hn[1];
            }
            *(f16x4*)&sH[buf ^ 1][colg * HS + 16 * w + quad * 4] = hh;
            // in-wave quad reduction of projection partials (verified R4/R6/R9)
            float p0 = pA[0] + pA[1];
            float p1 = pB[0] + pB[1];
            p0 += __shfl_xor(p0, 16, 64);
            p0 += __shfl_xor(p0, 32, 64);
            p1 += __shfl_xor(p1, 16, 64);
            p1 += __shfl_xor(p1, 32, 64);
            if (quad == 0) {
                sP[buf ^ 1][colg * 8 + 0 + w] = p0;
                sP[buf ^ 1][colg * 8 + 4 + w] = p1;
            }
        }
        __syncthreads();
        buf ^= 1;
        // distributed output reduction: 64 tasks over lanes<16 of all 4 waves.
        // sP double-buffered: step t+1 writes the OTHER buffer -> race-free.
        if (lane < 16) {
            f32x4 v = *(const f32x4*)&sP[buf][rrow * 8 + rcomp * 4];
            float p = (v[0] + v[1]) + (v[2] + v[3]) + bp;
            out[(size_t)(wg * ROWS + rrow) * (DEC_T * 2) + t * 2 + rcomp] = p;
        }
    }
}

extern "C" void kernel_launch(void* const* d_in, const int* in_sizes, int n_in,
                              void* d_out, int out_size, void* d_ws, size_t ws_size,
                              hipStream_t stream) {
    const float* traj = (const float*)d_in[0];
    const float* WihE = (const float*)d_in[1];
    const float* WhhE = (const float*)d_in[2];
    const float* bihE = (const float*)d_in[3];
    const float* bhhE = (const float*)d_in[4];
    const float* WihD = (const float*)d_in[5];
    const float* WhhD = (const float*)d_in[6];
    const float* bihD = (const float*)d_in[7];
    const float* bhhD = (const float*)d_in[8];
    const float* Wpos = (const float*)d_in[9];
    const float* bpos = (const float*)d_in[10];
    float* out = (float*)d_out;

    const int B = in_sizes[0] / (ENC_T * 2);   // 65536
    const int grid = B / ROWS;                 // 2048 workgroups, 32 rows each

    lstm_seq2seq<<<grid, 256, 0, stream>>>(traj, WihE, WhhE, bihE, bhhE,
                                           WihD, WhhD, bihD, bhhD, Wpos, bpos, out);
}

// Round 13
// 316.737 us; speedup vs baseline: 1.0541x; 1.0177x over previous
//
#include <hip/hip_runtime.h>

#define HID   64
#define ENC_T 20
#define DEC_T 30
#define ROWS  32   // batch rows per workgroup: two 16-row MFMA n-tiles per wave
#define HS    72   // sH row stride in f16 elems: 144B = 16B-aligned

typedef _Float16 f16;
typedef _Float16 f16x8 __attribute__((ext_vector_type(8)));
typedef _Float16 f16x4 __attribute__((ext_vector_type(4)));
typedef float  f32x4  __attribute__((ext_vector_type(4)));
typedef float  f32x2  __attribute__((ext_vector_type(2)));
typedef unsigned int   uint_t;

#if __has_builtin(__builtin_amdgcn_exp2f)
#define EXP2F(x) __builtin_amdgcn_exp2f(x)
#else
#define EXP2F(x) exp2f(x)
#endif
#if __has_builtin(__builtin_amdgcn_rcpf)
#define RCPF(x) __builtin_amdgcn_rcpf(x)
#else
#define RCPF(x) (1.0f / (x))
#endif

#define L2E 1.4426950408889634f

__device__ __forceinline__ f32x2 exp2_2(f32x2 x) {
    f32x2 r; r[0] = EXP2F(x[0]); r[1] = EXP2F(x[1]); return r;
}
// 8 pair-inverses with 2 rcp (R11 note: vector IR scalarizes — kept because the
// rcp-count reduction is the win; trans ~8.5 cyc/wave, mul ~2).
__device__ __forceinline__ void batch_inv4_pk(f32x2 D0, f32x2 D1, f32x2 D2, f32x2 D3,
                                              f32x2& i0, f32x2& i1, f32x2& i2, f32x2& i3) {
    f32x2 m01 = D0 * D1;
    f32x2 m23 = D2 * D3;
    f32x2 p   = m01 * m23;
    f32x2 r;
    r[0] = RCPF(p[0]);
    r[1] = RCPF(p[1]);
    f32x2 r01 = r * m23;
    f32x2 r23 = r * m01;
    i0 = r01 * D1;
    i1 = r01 * D0;
    i2 = r23 * D3;
    i3 = r23 * D2;
}
// One v_rcp for four scalar reciprocals (c-tanh denominators).
__device__ __forceinline__ f32x4 batch_inv4(float D0, float D1, float D2, float D3) {
    float m01 = D0 * D1;
    float m23 = D2 * D3;
    float r   = RCPF(m01 * m23);
    float r01 = r * m23;
    float r23 = r * m01;
    f32x4 o;
    o[0] = r01 * D1;
    o[1] = r01 * D0;
    o[2] = r23 * D3;
    o[3] = r23 * D2;
    return o;
}

// 8 consecutive fp32 (scaled) -> f16 frag
__device__ __forceinline__ f16x8 load8h(const float* __restrict__ p, float s) {
    f16x8 r;
    #pragma unroll
    for (int u = 0; u < 8; ++u) r[u] = (f16)(p[u] * s);
    return r;
}

// launch_bounds model (R2/R4/R6/R7/R10/R11): the 2nd arg caps the UNIFIED
// (VGPR+AGPR) budget at 512/N per wave; reported arch-VGPR ~ half of that.
// At (256,2) the allocator uses ~160 total -> only 3 waves/SIMD (38% occ)
// despite arch-VGPR 60. (256,4) caps total at 128; body true-need ~110-120
// -> should fit and guarantee 4 waves/SIMD. Canary: hbm_bytes (spill).
__global__ __launch_bounds__(256, 4)
void lstm_seq2seq(const float* __restrict__ traj,
                  const float* __restrict__ WihE, const float* __restrict__ WhhE,
                  const float* __restrict__ bihE, const float* __restrict__ bhhE,
                  const float* __restrict__ WihD, const float* __restrict__ WhhD,
                  const float* __restrict__ bihD, const float* __restrict__ bhhD,
                  const float* __restrict__ Wpos, const float* __restrict__ bpos,
                  float* __restrict__ out)
{
    __shared__ __align__(16) f16   sH[2][ROWS * HS];    // h (single f16), double-buffered
    __shared__ __align__(16) f16x4 sXh[ROWS * ENC_T + ENC_T]; // {xh0,xh1,xl0,xl1} + 20 zero slots
    __shared__ __align__(16) float sP[2][ROWS * 8];     // [row][comp*4 + wave] per-wave sums

    const int tid  = threadIdx.x;
    const int w    = tid >> 6;      // wave -> unit tile (units 16w..16w+15)
    const int lane = tid & 63;
    const int col  = lane & 15;     // n-index: batch row (group 0) for this lane
    const int quad = lane >> 4;     // m-quad: C rows = units 16w + quad*4 + r
    const int wg   = blockIdx.x;

    const float gsc[4] = { L2E, L2E, 2.0f * L2E, L2E };  // i,f,g(tanh),o pre-scales

    // ---- stage trajectory as preconverted f16 hi/lo blocks (once) ----
    {
        const float* src = traj + (size_t)wg * (ROWS * ENC_T * 2);
        for (int p = tid; p < ROWS * ENC_T; p += 256) {
            f32x2 xp = *(const f32x2*)(src + 2 * p);
            f16 xh0 = (f16)xp[0], xh1 = (f16)xp[1];
            f16x4 v;
            v[0] = xh0; v[1] = xh1;
            v[2] = (f16)(xp[0] - (float)xh0);
            v[3] = (f16)(xp[1] - (float)xh1);
            sXh[p] = v;
        }
        if (tid < ENC_T) {              // zero slots: quad!=0 lanes read here
            f16x4 zz = {};
            sXh[ROWS * ENC_T + tid] = zz;
        }
    }
    // ---- zero h buffer 0 ----
    {
        uint_t* hz = (uint_t*)&sH[0][0];
        for (int j = tid; j < ROWS * HS / 2; j += 256) hz[j] = 0;
    }

    // ---- encoder A-fragments (f16). bw[j][0..1]: Whh k-blocks (A[m=col][k]).
    //      bw[j][2]: x+bias fold block: k-slots {W0hi,W1hi,W0lo,W1lo,b_hi,b_lo} ----
    f16x8 bw[4][3];
    #pragma unroll
    for (int j = 0; j < 4; ++j) {
        int g = 64 * j + 16 * w + col;
        #pragma unroll
        for (int kb = 0; kb < 2; ++kb)
            bw[j][kb] = load8h(WhhE + g * 64 + kb * 32 + quad * 8, gsc[j]);
        float w0 = WihE[g * 2 + 0] * gsc[j];
        float w1 = WihE[g * 2 + 1] * gsc[j];
        float bs = (bihE[g] + bhhE[g]) * gsc[j];
        f16 w0h = (f16)w0, w1h = (f16)w1, bh = (f16)bs;
        f16 w0l = (f16)(w0 - (float)w0h);
        f16 w1l = (f16)(w1 - (float)w1h);
        f16 bl  = (f16)(bs - (float)bh);
        f16x8 a2 = {};
        if (quad == 0) {
            a2[0] = w0h; a2[1] = w1h; a2[2] = w0l; a2[3] = w1l; a2[4] = bh; a2[5] = bl;
        }
        bw[j][2] = a2;
    }

    // hoisted per-lane constants for the encoder B2 block
    const uint_t onesd = (quad == 0) ? 0x3C003C00u : 0u;     // f16 {1,1} or {0,0}
    const int xbase0 = (quad == 0) ? (col      * ENC_T) : (ROWS * ENC_T);  // g=0
    const int xbase1 = (quad == 0) ? ((col+16) * ENC_T) : (ROWS * ENC_T);  // g=1
    const f32x4 z4 = { 0.f, 0.f, 0.f, 0.f };                 // shared zero C

    const f32x2 one2  = { 1.f, 1.f };
    const f32x2 two2  = { 2.f, 2.f };
    const f32x2 mone2 = { -1.f, -1.f };
    const f32x2 msc2  = { -2.f * L2E, -2.f * L2E };

    f32x2 c2[2][2] = {{{0.f,0.f},{0.f,0.f}},{{0.f,0.f},{0.f,0.f}}};
    int buf = 0;

    __syncthreads();

    // =========================== ENCODER ===========================
    for (int t = 0; t < ENC_T; ++t) {
        #pragma unroll
        for (int g = 0; g < 2; ++g) {
            const int colg = col + 16 * g;
            union { f16x4 v; uint_t d[2]; } xfu;
            xfu.v = sXh[(g ? xbase1 : xbase0) + t];
            union { f16x8 v; uint_t d[4]; } b2u;
            b2u.d[0] = xfu.d[0];
            b2u.d[1] = xfu.d[1];
            b2u.d[2] = onesd;
            b2u.d[3] = 0;
            f16x8 b0 = *(const f16x8*)&sH[buf][colg * HS +  0 + quad * 8];
            f16x8 b1 = *(const f16x8*)&sH[buf][colg * HS + 32 + quad * 8];
            f32x4 acc[4];
            #pragma unroll
            for (int j = 0; j < 4; ++j) {
                acc[j] = __builtin_amdgcn_mfma_f32_16x16x32_f16(bw[j][2], b2u.v, z4, 0, 0, 0);
                acc[j] = __builtin_amdgcn_mfma_f32_16x16x32_f16(bw[j][0], b0, acc[j], 0, 0, 0);
                acc[j] = __builtin_amdgcn_mfma_f32_16x16x32_f16(bw[j][1], b1, acc[j], 0, 0, 0);
            }
            // elementwise (batched reciprocals; pairs kept for readability)
            f32x2 so2[2], cn2[2];
            #pragma unroll
            for (int rp = 0; rp < 2; ++rp) {
                f32x2 a0 = { acc[0][2*rp], acc[0][2*rp+1] };
                f32x2 a1 = { acc[1][2*rp], acc[1][2*rp+1] };
                f32x2 a2v = { acc[2][2*rp], acc[2][2*rp+1] };
                f32x2 a3 = { acc[3][2*rp], acc[3][2*rp+1] };
                f32x2 i0, i1, i2, i3;
                batch_inv4_pk(exp2_2(-a0) + one2, exp2_2(-a1) + one2,
                              exp2_2(-a2v) + one2, exp2_2(-a3) + one2,
                              i0, i1, i2, i3);
                f32x2 tg = __builtin_elementwise_fma(two2, i2, mone2);
                f32x2 cn = __builtin_elementwise_fma(i1, c2[g][rp], i0 * tg);
                c2[g][rp] = cn;
                cn2[rp] = cn;
                so2[rp] = i3;
            }
            float Dc[4];
            #pragma unroll
            for (int rp = 0; rp < 2; ++rp) {
                f32x2 xs = cn2[rp] * msc2;
                Dc[2*rp+0] = 1.f + EXP2F(fminf(fmaxf(xs[0], -30.f), 30.f));
                Dc[2*rp+1] = 1.f + EXP2F(fminf(fmaxf(xs[1], -30.f), 30.f));
            }
            f32x4 invc = batch_inv4(Dc[0], Dc[1], Dc[2], Dc[3]);
            f16x4 hh;
            #pragma unroll
            for (int rp = 0; rp < 2; ++rp) {
                f32x2 ic = { invc[2*rp], invc[2*rp+1] };
                f32x2 th = __builtin_elementwise_fma(two2, ic, mone2);
                f32x2 hn = so2[rp] * th;
                hh[2*rp+0] = (f16)hn[0];
                hh[2*rp+1] = (f16)hn[1];
            }
            *(f16x4*)&sH[buf ^ 1][colg * HS + 16 * w + quad * 4] = hh;
        }
        __syncthreads();
        buf ^= 1;
    }

    // ---- decoder A-fragments: Wc = (W_ih_dec + W_hh_dec)*gsc, f16 single.
    //      Bias as MFMA C-input (quad-indexed rows). ----
    f32x4 bD4[4];
    #pragma unroll
    for (int j = 0; j < 4; ++j) {
        int g = 64 * j + 16 * w + col;
        #pragma unroll
        for (int kb = 0; kb < 2; ++kb) {
            int off = g * 64 + kb * 32 + quad * 8;
            float tmp[8];
            #pragma unroll
            for (int u = 0; u < 8; ++u) tmp[u] = WihD[off + u] + WhhD[off + u];
            bw[j][kb] = load8h(tmp, gsc[j]);
        }
        #pragma unroll
        for (int r = 0; r < 4; ++r) {
            int gr = 64 * j + 16 * w + quad * 4 + r;   // C-row indexing
            bD4[j][r] = (bihD[gr] + bhhD[gr]) * gsc[j];
        }
    }

    // projection constants as packed pairs: this lane's 4 units
    f32x2 wpA2[2], wpB2[2];
    #pragma unroll
    for (int rp = 0; rp < 2; ++rp) {
        int u = 16 * w + quad * 4 + 2 * rp;
        wpA2[rp][0] = Wpos[u];       wpA2[rp][1] = Wpos[u + 1];        // comp 0
        wpB2[rp][0] = Wpos[64 + u];  wpB2[rp][1] = Wpos[64 + u + 1];   // comp 1
    }
    // distributed reducer constants: 64 tasks = 32 rows x 2 comps, lanes<16 of ALL 4 waves
    const int   rrow  = w * 8 + (lane >> 1);   // 0..31
    const int   rcomp = lane & 1;
    const float bp    = bpos[rcomp];

    // =========================== DECODER ===========================
    for (int t = 0; t < DEC_T; ++t) {
        #pragma unroll
        for (int g = 0; g < 2; ++g) {
            const int colg = col + 16 * g;
            f16x8 b0 = *(const f16x8*)&sH[buf][colg * HS +  0 + quad * 8];
            f16x8 b1 = *(const f16x8*)&sH[buf][colg * HS + 32 + quad * 8];
            f32x4 acc[4];
            #pragma unroll
            for (int j = 0; j < 4; ++j) {
                acc[j] = __builtin_amdgcn_mfma_f32_16x16x32_f16(bw[j][0], b0, bD4[j], 0, 0, 0);
                acc[j] = __builtin_amdgcn_mfma_f32_16x16x32_f16(bw[j][1], b1, acc[j], 0, 0, 0);
            }
            // elementwise (batched reciprocals)
            f32x2 so2[2], cn2[2];
            #pragma unroll
            for (int rp = 0; rp < 2; ++rp) {
                f32x2 a0 = { acc[0][2*rp], acc[0][2*rp+1] };
                f32x2 a1 = { acc[1][2*rp], acc[1][2*rp+1] };
                f32x2 a2v = { acc[2][2*rp], acc[2][2*rp+1] };
                f32x2 a3 = { acc[3][2*rp], acc[3][2*rp+1] };
                f32x2 i0, i1, i2, i3;
                batch_inv4_pk(exp2_2(-a0) + one2, exp2_2(-a1) + one2,
                              exp2_2(-a2v) + one2, exp2_2(-a3) + one2,
                              i0, i1, i2, i3);
                f32x2 tg = __builtin_elementwise_fma(two2, i2, mone2);
                f32x2 cn = __builtin_elementwise_fma(i1, c2[g][rp], i0 * tg);
                c2[g][rp] = cn;
                cn2[rp] = cn;
                so2[rp] = i3;
            }
            float Dc[4];
            #pragma unroll
            for (int rp = 0; rp < 2; ++rp) {
                f32x2 xs = cn2[rp] * msc2;
                Dc[2*rp+0] = 1.f + EXP2F(fminf(fmaxf(xs[0], -30.f), 30.f));
                Dc[2*rp+1] = 1.f + EXP2F(fminf(fmaxf(xs[1], -30.f), 30.f));
            }
            f32x4 invc = batch_inv4(Dc[0], Dc[1], Dc[2], Dc[3]);
            f16x4 hh;
            f32x2 pA = { 0.f, 0.f }, pB = { 0.f, 0.f };
            #pragma unroll
            for (int rp = 0; rp < 2; ++rp) {
                f32x2 ic = { invc[2*rp], invc[2*rp+1] };
                f32x2 th = __builtin_elementwise_fma(two2, ic, mone2);
                f32x2 hn = so2[rp] * th;
                pA = __builtin_elementwise_fma(hn, wpA2[rp], pA);
                pB = __builtin_elementwise_fma(hn, wpB2[rp], pB);
                hh[2*rp+0] = (f16)hn[0];
                hh[2*rp+1] = (f16)hn[1];
            }
            *(f16x4*)&sH[buf ^ 1][colg * HS + 16 * w + quad * 4] = hh;
            // in-wave quad reduction of projection partials (verified R4/R6/R9)
            float p0 = pA[0] + pA[1];
            float p1 = pB[0] + pB[1];
            p0 += __shfl_xor(p0, 16, 64);
            p0 += __shfl_xor(p0, 32, 64);
            p1 += __shfl_xor(p1, 16, 64);
            p1 += __shfl_xor(p1, 32, 64);
            if (quad == 0) {
                sP[buf ^ 1][colg * 8 + 0 + w] = p0;
                sP[buf ^ 1][colg * 8 + 4 + w] = p1;
            }
        }
        __syncthreads();
        buf ^= 1;
        // distributed output reduction: 64 tasks over lanes<16 of all 4 waves.
        // sP double-buffered: step t+1 writes the OTHER buffer -> race-free.
        if (lane < 16) {
            f32x4 v = *(const f32x4*)&sP[buf][rrow * 8 + rcomp * 4];
            float p = (v[0] + v[1]) + (v[2] + v[3]) + bp;
            out[(size_t)(wg * ROWS + rrow) * (DEC_T * 2) + t * 2 + rcomp] = p;
        }
    }
}

extern "C" void kernel_launch(void* const* d_in, const int* in_sizes, int n_in,
                              void* d_out, int out_size, void* d_ws, size_t ws_size,
                              hipStream_t stream) {
    const float* traj = (const float*)d_in[0];
    const float* WihE = (const float*)d_in[1];
    const float* WhhE = (const float*)d_in[2];
    const float* bihE = (const float*)d_in[3];
    const float* bhhE = (const float*)d_in[4];
    const float* WihD = (const float*)d_in[5];
    const float* WhhD = (const float*)d_in[6];
    const float* bihD = (const float*)d_in[7];
    const float* bhhD = (const float*)d_in[8];
    const float* Wpos = (const float*)d_in[9];
    const float* bpos = (const float*)d_in[10];
    float* out = (float*)d_out;

    const int B = in_sizes[0] / (ENC_T * 2);   // 65536
    const int grid = B / ROWS;                 // 2048 workgroups, 32 rows each

    lstm_seq2seq<<<grid, 256, 0, stream>>>(traj, WihE, WhhE, bihE, bhhE,
                                           WihD, WhhD, bihD, bhhD, Wpos, bpos, out);
}